// Round 11
// baseline (293.054 us; speedup 1.0000x reference)
//
#include <hip/hip_runtime.h>
#include <hip/hip_bf16.h>

#define BSZ 8
#define SEQ 8192
#define DIM 128
#define NCH 128   // chunks per sequence
#define CLEN 64   // tokens per chunk

typedef unsigned short u16;
typedef unsigned int u32;
typedef short bf16x8 __attribute__((ext_vector_type(8)));
typedef float f32x4  __attribute__((ext_vector_type(4)));
typedef float f32x16 __attribute__((ext_vector_type(16)));

__device__ __forceinline__ float us2f(u16 w){ union{u32 i;float f;}u; u.i=((u32)w)<<16; return u.f; }
__device__ __forceinline__ u16 f2us(float f){
  __hip_bfloat16 h = __float2bfloat16(f);
  union{ __hip_bfloat16 b; u16 s; }u; u.b=h; return u.s;
}
__device__ __forceinline__ float wred64(float v){
  #pragma unroll
  for (int o=1;o<64;o<<=1) v += __shfl_xor(v,o,64);
  return v;
}
__device__ __forceinline__ float red16(float v){
  v += __shfl_xor(v,1,64); v += __shfl_xor(v,2,64);
  v += __shfl_xor(v,4,64); v += __shfl_xor(v,8,64);
  return v;
}
__device__ __forceinline__ float sigmoidf_(float z){ return 1.f/(1.f+__expf(-z)); }
__device__ __forceinline__ float gelu_tanh(float x){
  float y = 0.7978845608028654f * fmaf(0.044715f*x, x*x, x);
  float e = __expf(2.f*y);
  float th = 1.f - 2.f/(e+1.f);
  return 0.5f*x*(1.f+th);
}
// wave-local LDS ordering: all prior ds ops complete before subsequent ones issue.
__device__ __forceinline__ void lds_fence(){
  asm volatile("s_waitcnt lgkmcnt(0)" ::: "memory");
  __builtin_amdgcn_sched_barrier(0);
}

// ---------------- K0: pack weights into MFMA fragment-linear order (bf16)
// 16x16x32 B-frag: fi = ((c*NB + n)*2 + k2)*64 + lane; elem j:
//   W[c*64 + k2*32 + (l>>4)*8 + j][n*16 + (l&15)]
__device__ __forceinline__ void pack_one(const float* __restrict__ W, int N,
                                         u16* __restrict__ out, int fi)
{
  int lane = fi & 63;
  int k2   = (fi >> 6) & 1;
  int cn   = fi >> 7;
  int NB   = N >> 4;
  int n    = cn % NB, c = cn / NB;
  int k0   = c*64 + k2*32 + (lane>>4)*8;
  int col  = n*16 + (lane&15);
  u16* o = out + (size_t)fi*8;
  #pragma unroll
  for (int j=0;j<8;++j) o[j] = f2us(W[(size_t)(k0+j)*N + col]);
}

// 32x32x16 A-frag (W^T as A): fi = ((ng*8 + ks)*64 + lane); elem j:
//   W[ks*16 + (l>>5)*8 + j][ng*32 + (l&31)]         (w1: K=128 rows, N=512 cols)
__device__ __forceinline__ void pack32A(const float* __restrict__ W, int N,
                                        u16* __restrict__ out, int fi)
{
  int lane = fi & 63;
  int ks   = (fi >> 6) & 7;
  int ng   = fi >> 9;
  int k0   = ks*16 + (lane>>5)*8;
  int col  = ng*32 + (lane&31);
  u16* o = out + (size_t)fi*8;
  #pragma unroll
  for (int j=0;j<8;++j) o[j] = f2us(W[(size_t)(k0+j)*N + col]);
}

// 32x32x16 B-frag: fi = ((ksg*4 + ot)*64 + lane); elem j:
//   W[ksg*16 + (l>>5)*8 + j][ot*32 + (l&31)]        (w2: K=512 rows, N=128 cols)
__device__ __forceinline__ void pack32B(const float* __restrict__ W, int N,
                                        u16* __restrict__ out, int fi)
{
  int lane = fi & 63;
  int ot   = (fi >> 6) & 3;
  int ksg  = fi >> 8;
  int k0   = ksg*16 + (lane>>5)*8;
  int col  = ot*32 + (lane&31);
  u16* o = out + (size_t)fi*8;
  #pragma unroll
  for (int j=0;j<8;++j) o[j] = f2us(W[(size_t)(k0+j)*N + col]);
}

// k_prep also computes the 6 per-sequence affine scalars in its last block.
__global__ __launch_bounds__(256) void k_prep(
    const float* __restrict__ w1, const float* __restrict__ w2, const float* __restrict__ wo,
    const float* __restrict__ win, const float* __restrict__ wi, const float* __restrict__ wr,
    u16* __restrict__ w1t, u16* __restrict__ w2t, u16* __restrict__ wot,
    u16* __restrict__ wint, u16* __restrict__ wit, u16* __restrict__ wrt,
    const float* __restrict__ c,
    const float* a0,const float* a1,const float* a2,const float* a3,const float* a4,const float* a5,
    const float* s0,const float* s1,const float* s2,const float* s3,const float* s4,const float* s5,
    float* __restrict__ aff)
{
  if (blockIdx.x == 104){
    int l = threadIdx.x;
    if (l < 64){
      const float* ws[6]={a0,a1,a2,a3,a4,a5};
      const float* bs[6]={s0,s1,s2,s3,s4,s5};
      for (int b=0;b<BSZ;++b){
        #pragma unroll
        for (int h=0;h<6;++h){
          float v = c[b*128+l]*ws[h][l] + c[b*128+64+l]*ws[h][64+l];
          v = wred64(v);
          if (l==0) aff[b*6+h] = v + bs[h][0];
        }
      }
    }
    return;
  }
  int i = blockIdx.x*256 + threadIdx.x;   // 104*256 = 26624 threads
  if      (i <  8192) pack32A(w1, 512, w1t, i);           // K=128,N=512 (A-frags)
  else if (i < 16384) pack32B(w2, 128, w2t, i-8192);      // K=512,N=128 (B-frags)
  else if (i < 20480) pack_one(wo, 128, wot, i-16384);    // K=256,N=128
  else if (i < 22528) pack_one(win,128, wint,i-20480);    // K=128,N=128
  else if (i < 24576) pack_one(wi, 128, wit, i-22528);
  else                pack_one(wr, 128, wrt, i-24576);
}

// -------------------- K1: LN + MFMA gates -> packed (a|b) + chunk summaries
__global__ __launch_bounds__(256,4) void k_pre(
    const float* __restrict__ xg, const u16* __restrict__ wint, const float* __restrict__ b_in,
    const float* __restrict__ pos, const u16* __restrict__ wit, const float* __restrict__ b_i,
    const u16* __restrict__ wrt, const float* __restrict__ b_r, const float* __restrict__ avec,
    const float* __restrict__ aff,
    u32* __restrict__ abg,
    float* __restrict__ Ag, float* __restrict__ Bfg, float* __restrict__ Bbg)
{
  __shared__ __align__(16) u32 abp[CLEN*DIM];   // 32 KB; first phase aliased as A_l
  u16* A_l = (u16*)abp;                         // [64][136] = 17.4 KB
  const int t  = threadIdx.x;
  const int b  = blockIdx.x >> 7;
  const int ck = blockIdx.x & (NCH-1);
  const size_t base = ((size_t)(b*SEQ + ck*CLEN))*DIM;
  const int lane=t&63, wv=t>>6, col=lane&15, quad=lane>>4;
  const int m0 = wv*16;

  // LN
  {
    const float s1p = 1.f + aff[b*6+0];
    const int cg=t&15, rg=t>>4, j0=cg*8, r0=rg*4;
    #pragma unroll
    for (int ii=0;ii<4;++ii){
      int r=r0+ii;
      const float* xo = xg + base + (size_t)r*DIM + j0;
      float4 a = *(const float4*)xo;
      float4 bq = *(const float4*)(xo+4);
      float o[8]={a.x,a.y,a.z,a.w,bq.x,bq.y,bq.z,bq.w};
      float s=0.f;
      #pragma unroll
      for (int j=0;j<8;++j) s+=o[j];
      s=red16(s); float m=s*(1.f/128.f);
      float q2=0.f;
      #pragma unroll
      for (int j=0;j<8;++j){ float d=o[j]-m; q2+=d*d; }
      q2=red16(q2); float var=q2*(1.f/128.f);
      float rs=rsqrtf(var+1e-6f);
      float vz=var*rs*rs;
      float tt2=s1p*rsqrtf(fmaf(s1p*s1p,vz,1e-6f));
      float sc=rs*tt2;
      u32 pk[4];
      #pragma unroll
      for (int q=0;q<4;++q){
        pk[q]= (u32)f2us((o[2*q]-m)*sc) | ((u32)f2us((o[2*q+1]-m)*sc)<<16);
      }
      *(uint4*)&A_l[r*136+j0] = make_uint4(pk[0],pk[1],pk[2],pk[3]);
    }
  }
  lds_fence();

  // mm B: u = lnh @ w_in
  f32x4 uacc[8];
  #pragma unroll
  for (int n=0;n<8;++n) uacc[n]=(f32x4){0.f,0.f,0.f,0.f};
  #pragma unroll
  for (int c=0;c<2;++c){
    #pragma unroll
    for (int k2=0;k2<2;++k2){
      bf16x8 av = *(const bf16x8*)&A_l[(m0+col)*136 + c*64 + k2*32 + quad*8];
      #pragma unroll
      for (int n=0;n<8;++n){
        bf16x8 bv = *(const bf16x8*)&wint[(size_t)(((c*8+n)*2+k2)*64+lane)*8];
        uacc[n] = __builtin_amdgcn_mfma_f32_16x16x32_bf16(av, bv, uacc[n], 0,0,0);
      }
    }
  }
  float u_c[8][4];
  #pragma unroll
  for (int n=0;n<8;++n){
    int nc = n*16 + col;
    float bi = b_in[nc];
    #pragma unroll
    for (int r=0;r<4;++r){
      int row = m0 + quad*4 + r;
      u_c[n][r] = uacc[n][r] + bi + pos[(size_t)(ck*CLEN+row)*DIM + nc];
    }
  }
  #pragma unroll
  for (int n=0;n<8;++n){
    #pragma unroll
    for (int r=0;r<4;++r)
      A_l[(m0+quad*4+r)*136 + n*16+col] = f2us(u_c[n][r]);
  }
  lds_fence();

  // mm C+D fused: gi, gr
  f32x4 gacc[8], racc[8];
  #pragma unroll
  for (int n=0;n<8;++n){ gacc[n]=(f32x4){0.f,0.f,0.f,0.f}; racc[n]=(f32x4){0.f,0.f,0.f,0.f}; }
  #pragma unroll
  for (int c=0;c<2;++c){
    #pragma unroll
    for (int k2=0;k2<2;++k2){
      bf16x8 av = *(const bf16x8*)&A_l[(m0+col)*136 + c*64 + k2*32 + quad*8];
      #pragma unroll
      for (int n=0;n<8;++n){
        bf16x8 bgi = *(const bf16x8*)&wit[(size_t)(((c*8+n)*2+k2)*64+lane)*8];
        gacc[n] = __builtin_amdgcn_mfma_f32_16x16x32_bf16(av, bgi, gacc[n], 0,0,0);
        bf16x8 bgr = *(const bf16x8*)&wrt[(size_t)(((c*8+n)*2+k2)*64+lane)*8];
        racc[n] = __builtin_amdgcn_mfma_f32_16x16x32_bf16(av, bgr, racc[n], 0,0,0);
      }
    }
  }
  __syncthreads();   // all A_l reads done -> safe to overwrite as abp

  // a_t, b_t -> packed LDS
  #pragma unroll
  for (int n=0;n<8;++n){
    int nc = n*16 + col;
    float la = __logf(avec[nc]);
    float br = b_r[nc];
    float bi = b_i[nc];
    #pragma unroll
    for (int r=0;r<4;++r){
      int row = m0 + quad*4 + r;
      float gi = sigmoidf_(gacc[n][r]+bi);
      float g  = sigmoidf_(racc[n][r]+br);
      float a  = __expf(8.f*g*la);
      float bb = sqrtf(fmaxf(1.f-a*a,0.f))*gi*u_c[n][r];
      abp[row*DIM+nc] = (u32)f2us(a) | ((u32)f2us(bb)<<16);
    }
  }
  __syncthreads();   // abp read cross-wave below

  // coalesced abg write
  {
    uint4* dst = (uint4*)(abg + base);
    const uint4* src = (const uint4*)abp;
    #pragma unroll
    for (int i=t;i<2048;i+=256) dst[i]=src[i];
  }

  // chunk-local scans -> summaries
  const int sbase = (b*NCH+ck)*DIM;
  if (t < 128){
    float h=0.f, p=1.f;
    #pragma unroll 4
    for (int tt=0;tt<CLEN;++tt){
      u32 v=abp[tt*DIM+t];
      float a=us2f((u16)v), bb=us2f((u16)(v>>16));
      h=fmaf(a,h,bb); p*=a;
    }
    Ag[sbase+t]=p; Bfg[sbase+t]=h;
  } else {
    int ch=t-128; float h=0.f;
    #pragma unroll 4
    for (int tt=CLEN-1;tt>=0;--tt){
      u32 v=abp[tt*DIM+ch];
      h=fmaf(us2f((u16)v),h,us2f((u16)(v>>16)));
    }
    Bbg[sbase+ch]=h;
  }
}

// -------------------- K2: seeded scan + MFMA out-proj + residual
// Seed computed IN-BLOCK (composition over chunk summaries, L2-hot) — the
// separate k_chunkscan launch and Hf/Hb round-trip are gone.
__global__ __launch_bounds__(256,4) void k_scan(
    const u32* __restrict__ abg,
    const float* __restrict__ Ag, const float* __restrict__ Bfg, const float* __restrict__ Bbg,
    const float* __restrict__ xg, const u16* __restrict__ wot, const float* __restrict__ b_out,
    const float* __restrict__ aff, float* __restrict__ outg)
{
  __shared__ __align__(16) u16 hcat[CLEN*264];    // 33.8 KB; later f32 C-tile
  const int t  = threadIdx.x;
  const int b  = blockIdx.x >> 7;
  const int ck = blockIdx.x & (NCH-1);
  const size_t base = ((size_t)(b*SEQ + ck*CLEN))*DIM;

  if (t<128){
    // seed: fwd composition over chunks 0..ck-1 (chunk 0 applied first)
    const float* pA = Ag  + (size_t)(b*NCH)*DIM + t;
    const float* pB = Bfg + (size_t)(b*NCH)*DIM + t;
    float h = 0.f;
    for (int cc=0; cc<ck; ++cc)
      h = fmaf(pA[(size_t)cc*DIM], h, pB[(size_t)cc*DIM]);
    const u32* p = abg + base + t;
    u32 v0=p[0], v1=p[128], v2=p[256], v3=p[384];
    #pragma unroll
    for (int g=0; g<16; ++g){
      u32 n0=0,n1=0,n2=0,n3=0;
      if (g<15){
        n0=p[(g*4+4)*128]; n1=p[(g*4+5)*128];
        n2=p[(g*4+6)*128]; n3=p[(g*4+7)*128];
      }
      h=fmaf(us2f((u16)v0),h,us2f((u16)(v0>>16))); hcat[(g*4+0)*264+t]=f2us(h);
      h=fmaf(us2f((u16)v1),h,us2f((u16)(v1>>16))); hcat[(g*4+1)*264+t]=f2us(h);
      h=fmaf(us2f((u16)v2),h,us2f((u16)(v2>>16))); hcat[(g*4+2)*264+t]=f2us(h);
      h=fmaf(us2f((u16)v3),h,us2f((u16)(v3>>16))); hcat[(g*4+3)*264+t]=f2us(h);
      v0=n0; v1=n1; v2=n2; v3=n3;
    }
  } else {
    int ch=t-128;
    // seed: bwd composition over chunks NCH-1..ck+1 (chunk NCH-1 applied first)
    const float* pA = Ag  + (size_t)(b*NCH)*DIM + ch;
    const float* pB = Bbg + (size_t)(b*NCH)*DIM + ch;
    float h = 0.f;
    for (int cc=NCH-1; cc>ck; --cc)
      h = fmaf(pA[(size_t)cc*DIM], h, pB[(size_t)cc*DIM]);
    const u32* p = abg + base + ch;
    u32 v0=p[63*128], v1=p[62*128], v2=p[61*128], v3=p[60*128];
    #pragma unroll
    for (int g=0; g<16; ++g){
      u32 n0=0,n1=0,n2=0,n3=0;
      if (g<15){
        n0=p[(59-g*4)*128]; n1=p[(58-g*4)*128];
        n2=p[(57-g*4)*128]; n3=p[(56-g*4)*128];
      }
      h=fmaf(us2f((u16)v0),h,us2f((u16)(v0>>16))); hcat[(63-g*4)*264+128+ch]=f2us(h);
      h=fmaf(us2f((u16)v1),h,us2f((u16)(v1>>16))); hcat[(62-g*4)*264+128+ch]=f2us(h);
      h=fmaf(us2f((u16)v2),h,us2f((u16)(v2>>16))); hcat[(61-g*4)*264+128+ch]=f2us(h);
      h=fmaf(us2f((u16)v3),h,us2f((u16)(v3>>16))); hcat[(60-g*4)*264+128+ch]=f2us(h);
      v0=n0; v1=n1; v2=n2; v3=n3;
    }
  }
  __syncthreads();

  const int lane=t&63, wv=t>>6, col=lane&15, quad=lane>>4;
  const int m0 = wv*16;
  f32x4 acc[8];
  #pragma unroll
  for (int n=0;n<8;++n) acc[n]=(f32x4){0.f,0.f,0.f,0.f};
  #pragma unroll
  for (int chk=0; chk<4; ++chk){
    #pragma unroll
    for (int k2=0;k2<2;++k2){
      bf16x8 av = *(const bf16x8*)&hcat[(m0+col)*264 + chk*64 + k2*32 + quad*8];
      #pragma unroll
      for (int n=0;n<8;++n){
        bf16x8 bv = *(const bf16x8*)&wot[(size_t)(((chk*8+n)*2+k2)*64+lane)*8];
        acc[n] = __builtin_amdgcn_mfma_f32_16x16x32_bf16(av, bv, acc[n], 0,0,0);
      }
    }
  }
  __syncthreads();
  float* pbuf = (float*)hcat;     // [64][128] f32 = 32 KB
  #pragma unroll
  for (int n=0;n<8;++n){
    #pragma unroll
    for (int r=0;r<4;++r)
      pbuf[(m0+quad*4+r)*128 + n*16+col] = acc[n][r];
  }
  __syncthreads();

  const float g1=aff[b*6+2];
  const float4* xv4 = (const float4*)(xg+base);
  float4* ov4 = (float4*)(outg+base);
  const float4* cv4 = (const float4*)pbuf;
  #pragma unroll
  for (int i=t;i<2048;i+=256){
    float4 cv = cv4[i];
    float4 xv = xv4[i];
    float4 bo = *(const float4*)&b_out[(i*4)&127];
    float4 r;
    r.x=fmaf(g1,cv.x+bo.x,xv.x); r.y=fmaf(g1,cv.y+bo.y,xv.y);
    r.z=fmaf(g1,cv.z+bo.z,xv.z); r.w=fmaf(g1,cv.w+bo.w,xv.w);
    ov4[i]=r;
  }
}

// -------------------- K3: cLN2 + fused MFMA gelu MLP + gated residual
// EXACT r9 body (verified passing r5/r9). 32x32x16, mm1 swapped, in-register
// gelu, 2 v_permlane32_swap per K-step; K-split across 4 waves; cross-wave
// f32 reduction via 32KB pbuf overlay (4 rounds of 16 tokens).
__global__ __launch_bounds__(256,2) void k_mlp(
    const u16* __restrict__ w1t, const float* __restrict__ b1v,
    const u16* __restrict__ w2t, const float* __restrict__ b2v,
    const float* __restrict__ aff, float* __restrict__ outg)
{
  __shared__ __align__(16) u32 smem4[8192];   // 32 KB: h2l (17.4 KB) then f32 pbuf
  u16* h2l = (u16*)smem4;          // [64][136] LN output, cross-wave
  const int t=threadIdx.x;
  const int b=blockIdx.x>>7;
  const size_t base=(size_t)blockIdx.x*CLEN*DIM;
  const int lane=t&63, wv=t>>6;
  const int l31=lane&31, h5=lane>>5;
  const float s2p=1.f+aff[b*6+3], b2a=aff[b*6+4], g2=aff[b*6+5];

  // step 0: h2 = (1+s2)*LN(x1)+b2 -> h2l (bf16)
  {
    const int cg=t&15, rg=t>>4, j0=cg*8, r0=rg*4;
    #pragma unroll
    for (int ii=0;ii<4;++ii){
      int r=r0+ii;
      const float* xo = outg + base + (size_t)r*DIM + j0;
      float4 a = *(const float4*)xo;
      float4 bq = *(const float4*)(xo+4);
      float o[8]={a.x,a.y,a.z,a.w,bq.x,bq.y,bq.z,bq.w};
      float s=0.f;
      #pragma unroll
      for (int j=0;j<8;++j) s+=o[j];
      s=red16(s); float m=s*(1.f/128.f);
      float q2=0.f;
      #pragma unroll
      for (int j=0;j<8;++j){ float d=o[j]-m; q2+=d*d; }
      q2=red16(q2); float rs=rsqrtf(q2*(1.f/128.f)+1e-6f);
      u32 pk[4];
      #pragma unroll
      for (int q=0;q<4;++q){
        float a0=fmaf((o[2*q]-m)*rs,   s2p, b2a);
        float a1=fmaf((o[2*q+1]-m)*rs, s2p, b2a);
        pk[q]= (u32)f2us(a0) | ((u32)f2us(a1)<<16);
      }
      *(uint4*)&h2l[r*136+j0] = make_uint4(pk[0],pk[1],pk[2],pk[3]);
    }
  }
  __syncthreads();   // h2l read cross-wave

  f32x16 acc2[2][4];   // [token-tile tt][out-col tile ot], this wave's K-slice
  #pragma unroll
  for (int m=0;m<2;++m)
    #pragma unroll
    for (int n=0;n<4;++n)
      #pragma unroll
      for (int r=0;r<16;++r) acc2[m][n][r]=0.f;

  for (int nt=0;nt<4;++nt){        // 32-col group of this wave's m1 slice
    bf16x8 w1A[8];
    #pragma unroll
    for (int ks=0;ks<8;++ks)
      w1A[ks] = *(const bf16x8*)&w1t[((size_t)((wv*4+nt)*8 + ks)*64 + lane)*8];
    #pragma unroll
    for (int tt=0;tt<2;++tt){
      // mm1 swapped: m1^T tile [32 m1cols][32 tokens]
      f32x16 a1;
      #pragma unroll
      for (int r=0;r<16;++r) a1[r]=0.f;
      #pragma unroll
      for (int ks=0;ks<8;++ks){
        bf16x8 hb = *(const bf16x8*)&h2l[(tt*32 + l31)*136 + ks*16 + h5*8];
        a1 = __builtin_amdgcn_mfma_f32_32x32x16_bf16(w1A[ks], hb, a1, 0,0,0);
      }
      // bias + gelu + pack
      u32 pk[8];
      #pragma unroll
      for (int q=0;q<4;++q){
        float4 bq = *(const float4*)&b1v[wv*128 + nt*32 + q*8 + h5*4];
        float g0=gelu_tanh(a1[4*q+0]+bq.x);
        float g1=gelu_tanh(a1[4*q+1]+bq.y);
        float g2_=gelu_tanh(a1[4*q+2]+bq.z);
        float g3=gelu_tanh(a1[4*q+3]+bq.w);
        pk[2*q+0]=(u32)f2us(g0)|((u32)f2us(g1)<<16);
        pk[2*q+1]=(u32)f2us(g2_)|((u32)f2us(g3)<<16);
      }
      // half-exchange (swap(a,b): a'=[a_lo|b_lo], b'=[a_hi|b_hi])
      asm volatile("v_permlane32_swap_b32 %0, %1" : "+v"(pk[0]), "+v"(pk[2]));
      asm volatile("v_permlane32_swap_b32 %0, %1" : "+v"(pk[1]), "+v"(pk[3]));
      asm volatile("v_permlane32_swap_b32 %0, %1" : "+v"(pk[4]), "+v"(pk[6]));
      asm volatile("v_permlane32_swap_b32 %0, %1" : "+v"(pk[5]), "+v"(pk[7]));
      union F8 { bf16x8 v; u32 u[4]; } A0, A1;
      A0.u[0]=pk[0]; A0.u[1]=pk[1]; A0.u[2]=pk[2]; A0.u[3]=pk[3];
      A1.u[0]=pk[4]; A1.u[1]=pk[5]; A1.u[2]=pk[6]; A1.u[3]=pk[7];
      // mm2 partials: ksg = wv*8 + nt*2 + {0,1}
      #pragma unroll
      for (int ot=0;ot<4;++ot){
        bf16x8 wb0 = *(const bf16x8*)&w2t[((size_t)((wv*8 + nt*2 + 0)*4 + ot)*64 + lane)*8];
        acc2[tt][ot] = __builtin_amdgcn_mfma_f32_32x32x16_bf16(A0.v, wb0, acc2[tt][ot], 0,0,0);
        bf16x8 wb1 = *(const bf16x8*)&w2t[((size_t)((wv*8 + nt*2 + 1)*4 + ot)*64 + lane)*8];
        acc2[tt][ot] = __builtin_amdgcn_mfma_f32_32x32x16_bf16(A1.v, wb1, acc2[tt][ot], 0,0,0);
      }
    }
  }
  __syncthreads();   // all h2l reads done; smem -> f32 pbuf

  // cross-wave K-reduction + epilogue: 4 rounds of 16 tokens
  float* pbuf = (float*)smem4;       // [4 waves][16][128] f32 = 32 KB
  const int lrow = (lane>>4)&3;
  const int cb   = (lane&15)*8;
  #pragma unroll
  for (int rt=0;rt<4;++rt){
    const int tt = rt>>1, gg = rt&1;
    if (rt) __syncthreads();
    #pragma unroll
    for (int ot=0;ot<4;++ot){
      #pragma unroll
      for (int q=0;q<2;++q){
        #pragma unroll
        for (int r=0;r<4;++r){
          int reg = gg*8 + q*4 + r;
          int tl  = q*8 + r + 4*h5;       // token within 16-row group
          pbuf[wv*2048 + tl*128 + ot*32 + l31] = acc2[tt][ot][reg];
        }
      }
    }
    __syncthreads();
    float s[8] = {0.f,0.f,0.f,0.f,0.f,0.f,0.f,0.f};
    #pragma unroll
    for (int p=0;p<4;++p){
      float4 x0 = *(const float4*)&pbuf[p*2048 + (4*wv+lrow)*128 + cb];
      float4 x1 = *(const float4*)&pbuf[p*2048 + (4*wv+lrow)*128 + cb + 4];
      s[0]+=x0.x; s[1]+=x0.y; s[2]+=x0.z; s[3]+=x0.w;
      s[4]+=x1.x; s[5]+=x1.y; s[6]+=x1.z; s[7]+=x1.w;
    }
    int grow = rt*16 + 4*wv + lrow;
    size_t gi = base + (size_t)grow*DIM + cb;
    float4 o0 = *(const float4*)&outg[gi];
    float4 o1 = *(const float4*)&outg[gi+4];
    float4 bb0 = *(const float4*)&b2v[cb];
    float4 bb1 = *(const float4*)&b2v[cb+4];
    float4 r0, r1;
    r0.x = fmaf(g2, s[0]+bb0.x, o0.x); r0.y = fmaf(g2, s[1]+bb0.y, o0.y);
    r0.z = fmaf(g2, s[2]+bb0.z, o0.z); r0.w = fmaf(g2, s[3]+bb0.w, o0.w);
    r1.x = fmaf(g2, s[4]+bb1.x, o1.x); r1.y = fmaf(g2, s[5]+bb1.y, o1.y);
    r1.z = fmaf(g2, s[6]+bb1.z, o1.z); r1.w = fmaf(g2, s[7]+bb1.w, o1.w);
    *(float4*)&outg[gi]   = r0;
    *(float4*)&outg[gi+4] = r1;
  }
}

// ----------------------------------------------------------------------------
extern "C" void kernel_launch(void* const* d_in, const int* in_sizes, int n_in,
                              void* d_out, int out_size, void* d_ws, size_t ws_size,
                              hipStream_t stream)
{
  (void)in_sizes; (void)n_in; (void)out_size; (void)ws_size;
  const float* x   =(const float*)d_in[0];
  const float* c   =(const float*)d_in[1];
  const float* c1sw=(const float*)d_in[2];  const float* c1sb=(const float*)d_in[3];
  const float* c1bw=(const float*)d_in[4];  const float* c1bb=(const float*)d_in[5];
  const float* g1w =(const float*)d_in[6];  const float* g1b =(const float*)d_in[7];
  const float* win =(const float*)d_in[8];  const float* binv=(const float*)d_in[9];
  const float* pos =(const float*)d_in[10];
  const float* wi  =(const float*)d_in[11]; const float* biv =(const float*)d_in[12];
  const float* wr  =(const float*)d_in[13]; const float* brv =(const float*)d_in[14];
  const float* av  =(const float*)d_in[15];
  const float* wout=(const float*)d_in[16]; const float* bout=(const float*)d_in[17];
  const float* c2sw=(const float*)d_in[18]; const float* c2sb=(const float*)d_in[19];
  const float* c2bw=(const float*)d_in[20]; const float* c2bb=(const float*)d_in[21];
  const float* g2w =(const float*)d_in[22]; const float* g2b =(const float*)d_in[23];
  const float* w1  =(const float*)d_in[24]; const float* b1v =(const float*)d_in[25];
  const float* w2  =(const float*)d_in[26]; const float* b2v =(const float*)d_in[27];

  // workspace layout (~36 MB total)
  float* wsf  = (float*)d_ws;
  float* Ag   = wsf;
  float* Bfg  = Ag   + 131072;
  float* Bbg  = Bfg  + 131072;
  float* aff  = Bbg  + 131072;       // 48 (pad 64)
  u16*   w1t  = (u16*)(aff + 64);    // 65536 u16, fragment-packed
  u16*   w2t  = w1t + 65536;         // 65536
  u16*   wot  = w2t + 65536;         // 32768
  u16*   wint = wot + 32768;         // 16384
  u16*   wit  = wint + 16384;
  u16*   wrt  = wit  + 16384;
  u32*   abg  = (u32*)(wrt + 16384); // [BSZ*SEQ*DIM] packed (a|b) = 33.5 MB

  float* outg = (float*)d_out;

  k_prep<<<dim3(105),dim3(256),0,stream>>>(w1,w2,wout,win,wi,wr,
                                           w1t,w2t,wot,wint,wit,wrt,
                                           c, c1sw,c1bw,g1w,c2sw,c2bw,g2w,
                                           c1sb,c1bb,g1b,c2sb,c2bb,g2b, aff);
  k_pre<<<dim3(BSZ*NCH),dim3(256),0,stream>>>(x,wint,binv,pos,wit,biv,wrt,brv,av,aff,
                                              abg, Ag,Bfg,Bbg);
  k_scan<<<dim3(BSZ*NCH),dim3(256),0,stream>>>(abg,Ag,Bfg,Bbg,x,wot,bout,aff,outg);
  k_mlp<<<dim3(BSZ*NCH),dim3(256),0,stream>>>(w1t,b1v,w2t,b2v,aff,outg);
}

// Round 12
// 267.118 us; speedup vs baseline: 1.0971x; 1.0971x over previous
//
#include <hip/hip_runtime.h>
#include <hip/hip_bf16.h>

#define BSZ 8
#define SEQ 8192
#define DIM 128
#define NCH 128   // chunks per sequence
#define CLEN 64   // tokens per chunk

typedef unsigned short u16;
typedef unsigned int u32;
typedef short bf16x8 __attribute__((ext_vector_type(8)));
typedef float f32x4  __attribute__((ext_vector_type(4)));
typedef float f32x16 __attribute__((ext_vector_type(16)));

__device__ __forceinline__ float us2f(u16 w){ union{u32 i;float f;}u; u.i=((u32)w)<<16; return u.f; }
__device__ __forceinline__ u16 f2us(float f){
  __hip_bfloat16 h = __float2bfloat16(f);
  union{ __hip_bfloat16 b; u16 s; }u; u.b=h; return u.s;
}
__device__ __forceinline__ float wred64(float v){
  #pragma unroll
  for (int o=1;o<64;o<<=1) v += __shfl_xor(v,o,64);
  return v;
}
__device__ __forceinline__ float red16(float v){
  v += __shfl_xor(v,1,64); v += __shfl_xor(v,2,64);
  v += __shfl_xor(v,4,64); v += __shfl_xor(v,8,64);
  return v;
}
__device__ __forceinline__ float sigmoidf_(float z){ return 1.f/(1.f+__expf(-z)); }
__device__ __forceinline__ float gelu_tanh(float x){
  float y = 0.7978845608028654f * fmaf(0.044715f*x, x*x, x);
  float e = __expf(2.f*y);
  float th = 1.f - 2.f/(e+1.f);
  return 0.5f*x*(1.f+th);
}
// wave-local LDS ordering: all prior ds ops complete before subsequent ones issue.
__device__ __forceinline__ void lds_fence(){
  asm volatile("s_waitcnt lgkmcnt(0)" ::: "memory");
  __builtin_amdgcn_sched_barrier(0);
}

// ---------------- K0: pack weights into MFMA fragment-linear order (bf16)
// 16x16x32 B-frag: fi = ((c*NB + n)*2 + k2)*64 + lane; elem j:
//   W[c*64 + k2*32 + (l>>4)*8 + j][n*16 + (l&15)]
__device__ __forceinline__ void pack_one(const float* __restrict__ W, int N,
                                         u16* __restrict__ out, int fi)
{
  int lane = fi & 63;
  int k2   = (fi >> 6) & 1;
  int cn   = fi >> 7;
  int NB   = N >> 4;
  int n    = cn % NB, c = cn / NB;
  int k0   = c*64 + k2*32 + (lane>>4)*8;
  int col  = n*16 + (lane&15);
  u16* o = out + (size_t)fi*8;
  #pragma unroll
  for (int j=0;j<8;++j) o[j] = f2us(W[(size_t)(k0+j)*N + col]);
}

// 32x32x16 A-frag (W^T as A): fi = ((ng*8 + ks)*64 + lane); elem j:
//   W[ks*16 + (l>>5)*8 + j][ng*32 + (l&31)]         (w1: K=128 rows, N=512 cols)
__device__ __forceinline__ void pack32A(const float* __restrict__ W, int N,
                                        u16* __restrict__ out, int fi)
{
  int lane = fi & 63;
  int ks   = (fi >> 6) & 7;
  int ng   = fi >> 9;
  int k0   = ks*16 + (lane>>5)*8;
  int col  = ng*32 + (lane&31);
  u16* o = out + (size_t)fi*8;
  #pragma unroll
  for (int j=0;j<8;++j) o[j] = f2us(W[(size_t)(k0+j)*N + col]);
}

// 32x32x16 B-frag: fi = ((ksg*4 + ot)*64 + lane); elem j:
//   W[ksg*16 + (l>>5)*8 + j][ot*32 + (l&31)]        (w2: K=512 rows, N=128 cols)
__device__ __forceinline__ void pack32B(const float* __restrict__ W, int N,
                                        u16* __restrict__ out, int fi)
{
  int lane = fi & 63;
  int ot   = (fi >> 6) & 3;
  int ksg  = fi >> 8;
  int k0   = ksg*16 + (lane>>5)*8;
  int col  = ot*32 + (lane&31);
  u16* o = out + (size_t)fi*8;
  #pragma unroll
  for (int j=0;j<8;++j) o[j] = f2us(W[(size_t)(k0+j)*N + col]);
}

// k_prep also computes the 6 per-sequence affine scalars in its last block.
__global__ __launch_bounds__(256) void k_prep(
    const float* __restrict__ w1, const float* __restrict__ w2, const float* __restrict__ wo,
    const float* __restrict__ win, const float* __restrict__ wi, const float* __restrict__ wr,
    u16* __restrict__ w1t, u16* __restrict__ w2t, u16* __restrict__ wot,
    u16* __restrict__ wint, u16* __restrict__ wit, u16* __restrict__ wrt,
    const float* __restrict__ c,
    const float* a0,const float* a1,const float* a2,const float* a3,const float* a4,const float* a5,
    const float* s0,const float* s1,const float* s2,const float* s3,const float* s4,const float* s5,
    float* __restrict__ aff)
{
  if (blockIdx.x == 104){
    int l = threadIdx.x;
    if (l < 64){
      const float* ws[6]={a0,a1,a2,a3,a4,a5};
      const float* bs[6]={s0,s1,s2,s3,s4,s5};
      for (int b=0;b<BSZ;++b){
        #pragma unroll
        for (int h=0;h<6;++h){
          float v = c[b*128+l]*ws[h][l] + c[b*128+64+l]*ws[h][64+l];
          v = wred64(v);
          if (l==0) aff[b*6+h] = v + bs[h][0];
        }
      }
    }
    return;
  }
  int i = blockIdx.x*256 + threadIdx.x;   // 104*256 = 26624 threads
  if      (i <  8192) pack32A(w1, 512, w1t, i);           // K=128,N=512 (A-frags)
  else if (i < 16384) pack32B(w2, 128, w2t, i-8192);      // K=512,N=128 (B-frags)
  else if (i < 20480) pack_one(wo, 128, wot, i-16384);    // K=256,N=128
  else if (i < 22528) pack_one(win,128, wint,i-20480);    // K=128,N=128
  else if (i < 24576) pack_one(wi, 128, wit, i-22528);
  else                pack_one(wr, 128, wrt, i-24576);
}

// -------------------- K1: LN + MFMA gates -> packed (a|b) + chunk summaries
__global__ __launch_bounds__(256,4) void k_pre(
    const float* __restrict__ xg, const u16* __restrict__ wint, const float* __restrict__ b_in,
    const float* __restrict__ pos, const u16* __restrict__ wit, const float* __restrict__ b_i,
    const u16* __restrict__ wrt, const float* __restrict__ b_r, const float* __restrict__ avec,
    const float* __restrict__ aff,
    u32* __restrict__ abg,
    float* __restrict__ Ag, float* __restrict__ Bfg, float* __restrict__ Bbg)
{
  __shared__ __align__(16) u32 abp[CLEN*DIM];   // 32 KB; first phase aliased as A_l
  u16* A_l = (u16*)abp;                         // [64][136] = 17.4 KB
  const int t  = threadIdx.x;
  const int b  = blockIdx.x >> 7;
  const int ck = blockIdx.x & (NCH-1);
  const size_t base = ((size_t)(b*SEQ + ck*CLEN))*DIM;
  const int lane=t&63, wv=t>>6, col=lane&15, quad=lane>>4;
  const int m0 = wv*16;

  // LN
  {
    const float s1p = 1.f + aff[b*6+0];
    const int cg=t&15, rg=t>>4, j0=cg*8, r0=rg*4;
    #pragma unroll
    for (int ii=0;ii<4;++ii){
      int r=r0+ii;
      const float* xo = xg + base + (size_t)r*DIM + j0;
      float4 a = *(const float4*)xo;
      float4 bq = *(const float4*)(xo+4);
      float o[8]={a.x,a.y,a.z,a.w,bq.x,bq.y,bq.z,bq.w};
      float s=0.f;
      #pragma unroll
      for (int j=0;j<8;++j) s+=o[j];
      s=red16(s); float m=s*(1.f/128.f);
      float q2=0.f;
      #pragma unroll
      for (int j=0;j<8;++j){ float d=o[j]-m; q2+=d*d; }
      q2=red16(q2); float var=q2*(1.f/128.f);
      float rs=rsqrtf(var+1e-6f);
      float vz=var*rs*rs;
      float tt2=s1p*rsqrtf(fmaf(s1p*s1p,vz,1e-6f));
      float sc=rs*tt2;
      u32 pk[4];
      #pragma unroll
      for (int q=0;q<4;++q){
        pk[q]= (u32)f2us((o[2*q]-m)*sc) | ((u32)f2us((o[2*q+1]-m)*sc)<<16);
      }
      *(uint4*)&A_l[r*136+j0] = make_uint4(pk[0],pk[1],pk[2],pk[3]);
    }
  }
  lds_fence();

  // mm B: u = lnh @ w_in
  f32x4 uacc[8];
  #pragma unroll
  for (int n=0;n<8;++n) uacc[n]=(f32x4){0.f,0.f,0.f,0.f};
  #pragma unroll
  for (int c=0;c<2;++c){
    #pragma unroll
    for (int k2=0;k2<2;++k2){
      bf16x8 av = *(const bf16x8*)&A_l[(m0+col)*136 + c*64 + k2*32 + quad*8];
      #pragma unroll
      for (int n=0;n<8;++n){
        bf16x8 bv = *(const bf16x8*)&wint[(size_t)(((c*8+n)*2+k2)*64+lane)*8];
        uacc[n] = __builtin_amdgcn_mfma_f32_16x16x32_bf16(av, bv, uacc[n], 0,0,0);
      }
    }
  }
  float u_c[8][4];
  #pragma unroll
  for (int n=0;n<8;++n){
    int nc = n*16 + col;
    float bi = b_in[nc];
    #pragma unroll
    for (int r=0;r<4;++r){
      int row = m0 + quad*4 + r;
      u_c[n][r] = uacc[n][r] + bi + pos[(size_t)(ck*CLEN+row)*DIM + nc];
    }
  }
  #pragma unroll
  for (int n=0;n<8;++n){
    #pragma unroll
    for (int r=0;r<4;++r)
      A_l[(m0+quad*4+r)*136 + n*16+col] = f2us(u_c[n][r]);
  }
  lds_fence();

  // mm C+D fused: gi, gr
  f32x4 gacc[8], racc[8];
  #pragma unroll
  for (int n=0;n<8;++n){ gacc[n]=(f32x4){0.f,0.f,0.f,0.f}; racc[n]=(f32x4){0.f,0.f,0.f,0.f}; }
  #pragma unroll
  for (int c=0;c<2;++c){
    #pragma unroll
    for (int k2=0;k2<2;++k2){
      bf16x8 av = *(const bf16x8*)&A_l[(m0+col)*136 + c*64 + k2*32 + quad*8];
      #pragma unroll
      for (int n=0;n<8;++n){
        bf16x8 bgi = *(const bf16x8*)&wit[(size_t)(((c*8+n)*2+k2)*64+lane)*8];
        gacc[n] = __builtin_amdgcn_mfma_f32_16x16x32_bf16(av, bgi, gacc[n], 0,0,0);
        bf16x8 bgr = *(const bf16x8*)&wrt[(size_t)(((c*8+n)*2+k2)*64+lane)*8];
        racc[n] = __builtin_amdgcn_mfma_f32_16x16x32_bf16(av, bgr, racc[n], 0,0,0);
      }
    }
  }
  __syncthreads();   // all A_l reads done -> safe to overwrite as abp

  // a_t, b_t -> packed LDS
  #pragma unroll
  for (int n=0;n<8;++n){
    int nc = n*16 + col;
    float la = __logf(avec[nc]);
    float br = b_r[nc];
    float bi = b_i[nc];
    #pragma unroll
    for (int r=0;r<4;++r){
      int row = m0 + quad*4 + r;
      float gi = sigmoidf_(gacc[n][r]+bi);
      float g  = sigmoidf_(racc[n][r]+br);
      float a  = __expf(8.f*g*la);
      float bb = sqrtf(fmaxf(1.f-a*a,0.f))*gi*u_c[n][r];
      abp[row*DIM+nc] = (u32)f2us(a) | ((u32)f2us(bb)<<16);
    }
  }
  __syncthreads();   // abp read cross-wave below

  // coalesced abg write
  {
    uint4* dst = (uint4*)(abg + base);
    const uint4* src = (const uint4*)abp;
    #pragma unroll
    for (int i=t;i<2048;i+=256) dst[i]=src[i];
  }

  // chunk-local scans -> summaries
  const int sbase = (b*NCH+ck)*DIM;
  if (t < 128){
    float h=0.f, p=1.f;
    #pragma unroll 4
    for (int tt=0;tt<CLEN;++tt){
      u32 v=abp[tt*DIM+t];
      float a=us2f((u16)v), bb=us2f((u16)(v>>16));
      h=fmaf(a,h,bb); p*=a;
    }
    Ag[sbase+t]=p; Bfg[sbase+t]=h;
  } else {
    int ch=t-128; float h=0.f;
    #pragma unroll 4
    for (int tt=CLEN-1;tt>=0;--tt){
      u32 v=abp[tt*DIM+ch];
      h=fmaf(us2f((u16)v),h,us2f((u16)(v>>16)));
    }
    Bbg[sbase+ch]=h;
  }
}

// ------------------- K2: segmented prefix over chunk summaries
__global__ __launch_bounds__(1024) void k_chunkscan(
    const float* __restrict__ Ag, const float* __restrict__ Bfg, const float* __restrict__ Bbg,
    float* __restrict__ Hf, float* __restrict__ Hb)
{
  __shared__ float sP[8][128], sS[8][128];
  const int dir = blockIdx.x >> 3, b = blockIdx.x & 7;
  const int t = threadIdx.x, seg = t>>7, ch = t&127;
  const size_t cbase = (size_t)b*NCH*DIM + ch;
  float P=1.f, S=0.f;
  if (dir==0){
    #pragma unroll 4
    for (int j=0;j<16;++j){
      size_t i = cbase + (size_t)(seg*16+j)*DIM;
      float a=Ag[i]; S=fmaf(a,S,Bfg[i]); P*=a;
    }
  } else {
    #pragma unroll 4
    for (int j=15;j>=0;--j){
      size_t i = cbase + (size_t)(seg*16+j)*DIM;
      float a=Ag[i]; S=fmaf(a,S,Bbg[i]); P*=a;
    }
  }
  sP[seg][ch]=P; sS[seg][ch]=S;
  __syncthreads();
  float h=0.f;
  if (dir==0){ for (int s=0;s<seg;++s) h=fmaf(sP[s][ch],h,sS[s][ch]); }
  else       { for (int s=7;s>seg;--s) h=fmaf(sP[s][ch],h,sS[s][ch]); }
  if (dir==0){
    #pragma unroll 4
    for (int j=0;j<16;++j){
      size_t i = cbase + (size_t)(seg*16+j)*DIM;
      Hf[i]=h; h=fmaf(Ag[i],h,Bfg[i]);
    }
  } else {
    #pragma unroll 4
    for (int j=15;j>=0;--j){
      size_t i = cbase + (size_t)(seg*16+j)*DIM;
      Hb[i]=h; h=fmaf(Ag[i],h,Bbg[i]);
    }
  }
}

// -------------------- K3: seeded scan (direct-global, prefetched) + MFMA out-proj
__global__ __launch_bounds__(256,4) void k_scan(
    const u32* __restrict__ abg,
    const float* __restrict__ Hf, const float* __restrict__ Hb,
    const float* __restrict__ xg, const u16* __restrict__ wot, const float* __restrict__ b_out,
    const float* __restrict__ aff, float* __restrict__ outg)
{
  __shared__ __align__(16) u16 hcat[CLEN*264];    // 33.8 KB; later f32 C-tile
  const int t  = threadIdx.x;
  const int b  = blockIdx.x >> 7;
  const int ck = blockIdx.x & (NCH-1);
  const size_t base = ((size_t)(b*SEQ + ck*CLEN))*DIM;
  const int pbase=(b*NCH+ck)*DIM;

  if (t<128){
    const u32* p = abg + base + t;
    float h = Hf[pbase+t];
    u32 v0=p[0], v1=p[128], v2=p[256], v3=p[384];
    #pragma unroll
    for (int g=0; g<16; ++g){
      u32 n0=0,n1=0,n2=0,n3=0;
      if (g<15){
        n0=p[(g*4+4)*128]; n1=p[(g*4+5)*128];
        n2=p[(g*4+6)*128]; n3=p[(g*4+7)*128];
      }
      h=fmaf(us2f((u16)v0),h,us2f((u16)(v0>>16))); hcat[(g*4+0)*264+t]=f2us(h);
      h=fmaf(us2f((u16)v1),h,us2f((u16)(v1>>16))); hcat[(g*4+1)*264+t]=f2us(h);
      h=fmaf(us2f((u16)v2),h,us2f((u16)(v2>>16))); hcat[(g*4+2)*264+t]=f2us(h);
      h=fmaf(us2f((u16)v3),h,us2f((u16)(v3>>16))); hcat[(g*4+3)*264+t]=f2us(h);
      v0=n0; v1=n1; v2=n2; v3=n3;
    }
  } else {
    int ch=t-128;
    const u32* p = abg + base + ch;
    float h = Hb[pbase+ch];
    u32 v0=p[63*128], v1=p[62*128], v2=p[61*128], v3=p[60*128];
    #pragma unroll
    for (int g=0; g<16; ++g){
      u32 n0=0,n1=0,n2=0,n3=0;
      if (g<15){
        n0=p[(59-g*4)*128]; n1=p[(58-g*4)*128];
        n2=p[(57-g*4)*128]; n3=p[(56-g*4)*128];
      }
      h=fmaf(us2f((u16)v0),h,us2f((u16)(v0>>16))); hcat[(63-g*4)*264+128+ch]=f2us(h);
      h=fmaf(us2f((u16)v1),h,us2f((u16)(v1>>16))); hcat[(62-g*4)*264+128+ch]=f2us(h);
      h=fmaf(us2f((u16)v2),h,us2f((u16)(v2>>16))); hcat[(61-g*4)*264+128+ch]=f2us(h);
      h=fmaf(us2f((u16)v3),h,us2f((u16)(v3>>16))); hcat[(60-g*4)*264+128+ch]=f2us(h);
      v0=n0; v1=n1; v2=n2; v3=n3;
    }
  }
  __syncthreads();

  const int lane=t&63, wv=t>>6, col=lane&15, quad=lane>>4;
  const int m0 = wv*16;
  f32x4 acc[8];
  #pragma unroll
  for (int n=0;n<8;++n) acc[n]=(f32x4){0.f,0.f,0.f,0.f};
  #pragma unroll
  for (int chk=0; chk<4; ++chk){
    #pragma unroll
    for (int k2=0;k2<2;++k2){
      bf16x8 av = *(const bf16x8*)&hcat[(m0+col)*264 + chk*64 + k2*32 + quad*8];
      #pragma unroll
      for (int n=0;n<8;++n){
        bf16x8 bv = *(const bf16x8*)&wot[(size_t)(((chk*8+n)*2+k2)*64+lane)*8];
        acc[n] = __builtin_amdgcn_mfma_f32_16x16x32_bf16(av, bv, acc[n], 0,0,0);
      }
    }
  }
  __syncthreads();
  float* pbuf = (float*)hcat;     // [64][128] f32 = 32 KB
  #pragma unroll
  for (int n=0;n<8;++n){
    #pragma unroll
    for (int r=0;r<4;++r)
      pbuf[(m0+quad*4+r)*128 + n*16+col] = acc[n][r];
  }
  __syncthreads();

  const float g1=aff[b*6+2];
  const float4* xv4 = (const float4*)(xg+base);
  float4* ov4 = (float4*)(outg+base);
  const float4* cv4 = (const float4*)pbuf;
  #pragma unroll
  for (int i=t;i<2048;i+=256){
    float4 cv = cv4[i];
    float4 xv = xv4[i];
    float4 bo = *(const float4*)&b_out[(i*4)&127];
    float4 r;
    r.x=fmaf(g1,cv.x+bo.x,xv.x); r.y=fmaf(g1,cv.y+bo.y,xv.y);
    r.z=fmaf(g1,cv.z+bo.z,xv.z); r.w=fmaf(g1,cv.w+bo.w,xv.w);
    ov4[i]=r;
  }
}

// -------------------- K4: cLN2 + fused MFMA gelu MLP + gated residual
// EXACT r9 body + T5 s_setprio around MFMA clusters (waves are barrier-free
// through the main loop -> phase-diverse -> setprio regime applies).
__global__ __launch_bounds__(256,2) void k_mlp(
    const u16* __restrict__ w1t, const float* __restrict__ b1v,
    const u16* __restrict__ w2t, const float* __restrict__ b2v,
    const float* __restrict__ aff, float* __restrict__ outg)
{
  __shared__ __align__(16) u32 smem4[8192];   // 32 KB: h2l (17.4 KB) then f32 pbuf
  u16* h2l = (u16*)smem4;          // [64][136] LN output, cross-wave
  const int t=threadIdx.x;
  const int b=blockIdx.x>>7;
  const size_t base=(size_t)blockIdx.x*CLEN*DIM;
  const int lane=t&63, wv=t>>6;
  const int l31=lane&31, h5=lane>>5;
  const float s2p=1.f+aff[b*6+3], b2a=aff[b*6+4], g2=aff[b*6+5];

  // step 0: h2 = (1+s2)*LN(x1)+b2 -> h2l (bf16)
  {
    const int cg=t&15, rg=t>>4, j0=cg*8, r0=rg*4;
    #pragma unroll
    for (int ii=0;ii<4;++ii){
      int r=r0+ii;
      const float* xo = outg + base + (size_t)r*DIM + j0;
      float4 a = *(const float4*)xo;
      float4 bq = *(const float4*)(xo+4);
      float o[8]={a.x,a.y,a.z,a.w,bq.x,bq.y,bq.z,bq.w};
      float s=0.f;
      #pragma unroll
      for (int j=0;j<8;++j) s+=o[j];
      s=red16(s); float m=s*(1.f/128.f);
      float q2=0.f;
      #pragma unroll
      for (int j=0;j<8;++j){ float d=o[j]-m; q2+=d*d; }
      q2=red16(q2); float rs=rsqrtf(q2*(1.f/128.f)+1e-6f);
      u32 pk[4];
      #pragma unroll
      for (int q=0;q<4;++q){
        float a0=fmaf((o[2*q]-m)*rs,   s2p, b2a);
        float a1=fmaf((o[2*q+1]-m)*rs, s2p, b2a);
        pk[q]= (u32)f2us(a0) | ((u32)f2us(a1)<<16);
      }
      *(uint4*)&h2l[r*136+j0] = make_uint4(pk[0],pk[1],pk[2],pk[3]);
    }
  }
  __syncthreads();   // h2l read cross-wave

  f32x16 acc2[2][4];   // [token-tile tt][out-col tile ot], this wave's K-slice
  #pragma unroll
  for (int m=0;m<2;++m)
    #pragma unroll
    for (int n=0;n<4;++n)
      #pragma unroll
      for (int r=0;r<16;++r) acc2[m][n][r]=0.f;

  for (int nt=0;nt<4;++nt){        // 32-col group of this wave's m1 slice
    bf16x8 w1A[8];
    #pragma unroll
    for (int ks=0;ks<8;++ks)
      w1A[ks] = *(const bf16x8*)&w1t[((size_t)((wv*4+nt)*8 + ks)*64 + lane)*8];
    #pragma unroll
    for (int tt=0;tt<2;++tt){
      // mm1 swapped: m1^T tile [32 m1cols][32 tokens]
      f32x16 a1;
      #pragma unroll
      for (int r=0;r<16;++r) a1[r]=0.f;
      __builtin_amdgcn_s_setprio(1);
      #pragma unroll
      for (int ks=0;ks<8;++ks){
        bf16x8 hb = *(const bf16x8*)&h2l[(tt*32 + l31)*136 + ks*16 + h5*8];
        a1 = __builtin_amdgcn_mfma_f32_32x32x16_bf16(w1A[ks], hb, a1, 0,0,0);
      }
      __builtin_amdgcn_s_setprio(0);
      // bias + gelu + pack
      u32 pk[8];
      #pragma unroll
      for (int q=0;q<4;++q){
        float4 bq = *(const float4*)&b1v[wv*128 + nt*32 + q*8 + h5*4];
        float g0=gelu_tanh(a1[4*q+0]+bq.x);
        float g1=gelu_tanh(a1[4*q+1]+bq.y);
        float g2_=gelu_tanh(a1[4*q+2]+bq.z);
        float g3=gelu_tanh(a1[4*q+3]+bq.w);
        pk[2*q+0]=(u32)f2us(g0)|((u32)f2us(g1)<<16);
        pk[2*q+1]=(u32)f2us(g2_)|((u32)f2us(g3)<<16);
      }
      // half-exchange (swap(a,b): a'=[a_lo|b_lo], b'=[a_hi|b_hi])
      asm volatile("v_permlane32_swap_b32 %0, %1" : "+v"(pk[0]), "+v"(pk[2]));
      asm volatile("v_permlane32_swap_b32 %0, %1" : "+v"(pk[1]), "+v"(pk[3]));
      asm volatile("v_permlane32_swap_b32 %0, %1" : "+v"(pk[4]), "+v"(pk[6]));
      asm volatile("v_permlane32_swap_b32 %0, %1" : "+v"(pk[5]), "+v"(pk[7]));
      union F8 { bf16x8 v; u32 u[4]; } A0, A1;
      A0.u[0]=pk[0]; A0.u[1]=pk[1]; A0.u[2]=pk[2]; A0.u[3]=pk[3];
      A1.u[0]=pk[4]; A1.u[1]=pk[5]; A1.u[2]=pk[6]; A1.u[3]=pk[7];
      // mm2 partials: ksg = wv*8 + nt*2 + {0,1}
      __builtin_amdgcn_s_setprio(1);
      #pragma unroll
      for (int ot=0;ot<4;++ot){
        bf16x8 wb0 = *(const bf16x8*)&w2t[((size_t)((wv*8 + nt*2 + 0)*4 + ot)*64 + lane)*8];
        acc2[tt][ot] = __builtin_amdgcn_mfma_f32_32x32x16_bf16(A0.v, wb0, acc2[tt][ot], 0,0,0);
        bf16x8 wb1 = *(const bf16x8*)&w2t[((size_t)((wv*8 + nt*2 + 1)*4 + ot)*64 + lane)*8];
        acc2[tt][ot] = __builtin_amdgcn_mfma_f32_32x32x16_bf16(A1.v, wb1, acc2[tt][ot], 0,0,0);
      }
      __builtin_amdgcn_s_setprio(0);
    }
  }
  __syncthreads();   // all h2l reads done; smem -> f32 pbuf

  // cross-wave K-reduction + epilogue: 4 rounds of 16 tokens
  float* pbuf = (float*)smem4;       // [4 waves][16][128] f32 = 32 KB
  const int lrow = (lane>>4)&3;
  const int cb   = (lane&15)*8;
  #pragma unroll
  for (int rt=0;rt<4;++rt){
    const int tt = rt>>1, gg = rt&1;
    if (rt) __syncthreads();
    #pragma unroll
    for (int ot=0;ot<4;++ot){
      #pragma unroll
      for (int q=0;q<2;++q){
        #pragma unroll
        for (int r=0;r<4;++r){
          int reg = gg*8 + q*4 + r;
          int tl  = q*8 + r + 4*h5;       // token within 16-row group
          pbuf[wv*2048 + tl*128 + ot*32 + l31] = acc2[tt][ot][reg];
        }
      }
    }
    __syncthreads();
    float s[8] = {0.f,0.f,0.f,0.f,0.f,0.f,0.f,0.f};
    #pragma unroll
    for (int p=0;p<4;++p){
      float4 x0 = *(const float4*)&pbuf[p*2048 + (4*wv+lrow)*128 + cb];
      float4 x1 = *(const float4*)&pbuf[p*2048 + (4*wv+lrow)*128 + cb + 4];
      s[0]+=x0.x; s[1]+=x0.y; s[2]+=x0.z; s[3]+=x0.w;
      s[4]+=x1.x; s[5]+=x1.y; s[6]+=x1.z; s[7]+=x1.w;
    }
    int grow = rt*16 + 4*wv + lrow;
    size_t gi = base + (size_t)grow*DIM + cb;
    float4 o0 = *(const float4*)&outg[gi];
    float4 o1 = *(const float4*)&outg[gi+4];
    float4 bb0 = *(const float4*)&b2v[cb];
    float4 bb1 = *(const float4*)&b2v[cb+4];
    float4 r0, r1;
    r0.x = fmaf(g2, s[0]+bb0.x, o0.x); r0.y = fmaf(g2, s[1]+bb0.y, o0.y);
    r0.z = fmaf(g2, s[2]+bb0.z, o0.z); r0.w = fmaf(g2, s[3]+bb0.w, o0.w);
    r1.x = fmaf(g2, s[4]+bb1.x, o1.x); r1.y = fmaf(g2, s[5]+bb1.y, o1.y);
    r1.z = fmaf(g2, s[6]+bb1.z, o1.z); r1.w = fmaf(g2, s[7]+bb1.w, o1.w);
    *(float4*)&outg[gi]   = r0;
    *(float4*)&outg[gi+4] = r1;
  }
}

// ----------------------------------------------------------------------------
extern "C" void kernel_launch(void* const* d_in, const int* in_sizes, int n_in,
                              void* d_out, int out_size, void* d_ws, size_t ws_size,
                              hipStream_t stream)
{
  (void)in_sizes; (void)n_in; (void)out_size; (void)ws_size;
  const float* x   =(const float*)d_in[0];
  const float* c   =(const float*)d_in[1];
  const float* c1sw=(const float*)d_in[2];  const float* c1sb=(const float*)d_in[3];
  const float* c1bw=(const float*)d_in[4];  const float* c1bb=(const float*)d_in[5];
  const float* g1w =(const float*)d_in[6];  const float* g1b =(const float*)d_in[7];
  const float* win =(const float*)d_in[8];  const float* binv=(const float*)d_in[9];
  const float* pos =(const float*)d_in[10];
  const float* wi  =(const float*)d_in[11]; const float* biv =(const float*)d_in[12];
  const float* wr  =(const float*)d_in[13]; const float* brv =(const float*)d_in[14];
  const float* av  =(const float*)d_in[15];
  const float* wout=(const float*)d_in[16]; const float* bout=(const float*)d_in[17];
  const float* c2sw=(const float*)d_in[18]; const float* c2sb=(const float*)d_in[19];
  const float* c2bw=(const float*)d_in[20]; const float* c2bb=(const float*)d_in[21];
  const float* g2w =(const float*)d_in[22]; const float* g2b =(const float*)d_in[23];
  const float* w1  =(const float*)d_in[24]; const float* b1v =(const float*)d_in[25];
  const float* w2  =(const float*)d_in[26]; const float* b2v =(const float*)d_in[27];

  // workspace layout (~36.6 MB total)
  float* wsf  = (float*)d_ws;
  float* Ag   = wsf;
  float* Bfg  = Ag   + 131072;
  float* Bbg  = Bfg  + 131072;
  float* Hf   = Bbg  + 131072;
  float* Hb   = Hf   + 131072;
  float* aff  = Hb   + 131072;       // 48 (pad 64)
  u16*   w1t  = (u16*)(aff + 64);    // 65536 u16, fragment-packed
  u16*   w2t  = w1t + 65536;         // 65536
  u16*   wot  = w2t + 65536;         // 32768
  u16*   wint = wot + 32768;         // 16384
  u16*   wit  = wint + 16384;
  u16*   wrt  = wit  + 16384;
  u32*   abg  = (u32*)(wrt + 16384); // [BSZ*SEQ*DIM] packed (a|b) = 33.5 MB

  float* outg = (float*)d_out;

  k_prep<<<dim3(105),dim3(256),0,stream>>>(w1,w2,wout,win,wi,wr,
                                           w1t,w2t,wot,wint,wit,wrt,
                                           c, c1sw,c1bw,g1w,c2sw,c2bw,g2w,
                                           c1sb,c1bb,g1b,c2sb,c2bb,g2b, aff);
  k_pre<<<dim3(BSZ*NCH),dim3(256),0,stream>>>(x,wint,binv,pos,wit,biv,wrt,brv,av,aff,
                                              abg, Ag,Bfg,Bbg);
  k_chunkscan<<<dim3(16),dim3(1024),0,stream>>>(Ag,Bfg,Bbg,Hf,Hb);
  k_scan<<<dim3(BSZ*NCH),dim3(256),0,stream>>>(abg,Hf,Hb,x,wot,bout,aff,outg);
  k_mlp<<<dim3(BSZ*NCH),dim3(256),0,stream>>>(w1t,b1v,w2t,b2v,aff,outg);
}